// Round 7
// baseline (839.467 us; speedup 1.0000x reference)
//
#include <hip/hip_runtime.h>
#include <math.h>

#define D       256
#define NROWS   32768      // 8 * 4096
#define CODES   8192
#define QOFF    8388608    // index output offset (floats) in d_out

// ---------------- coarse GEMM config ----------------
#define BM      256
#define BN      128
#define NSPL    4
#define SPLC    (CODES / NSPL)    // 2048
#define NCHUNK  (SPLC / BN)       // 16
#define NBLK    512               // 128 rowTiles * NSPL
#define LQ      2048              // LDS candidate buffer entries (pass 2)

// rigorous collect margin (2M): 2*2*(2u+u^2)*||x||*||e||max, u=2^-9 (bf16 rn)
#define MARG_COEF 0.016f
#define MARG_ABS  0.10f

// ---------------- ws layout (bytes) ----------------
#define OFF_AH    0ull               // 32768*512 = 16777216
#define OFF_X2    16777216ull
#define OFF_NX    16908288ull
#define OFF_E2    17039360ull
#define OFF_RM    17072128ull        // 32768*4 (monotone-encoded float bits)
#define OFF_PK    17203200ull        // 32768*8
#define OFF_MISC  17465344ull        // [1]=ovCnt, [2]=neMaxBits
#define OFF_BCNT  17465600ull        // 512*4
#define OFF_CAND  17469696ull        // 4B entries: NBLK*LQ segmented + overflow
#define WS_NEED4  25858304ull        // OFF_CAND + 4MB segs + 4MB overflow (< proven 30MB)

typedef __attribute__((ext_vector_type(8)))  short bf16x8;
typedef __attribute__((ext_vector_type(16))) float f32x16;

__device__ __forceinline__ void gload16(const void* g, void* l) {
  __builtin_amdgcn_global_load_lds(
      (const __attribute__((address_space(1))) unsigned int*)g,
      (__attribute__((address_space(3))) unsigned int*)l, 16, 0, 0);
}

__device__ __forceinline__ unsigned short bf16rn(float x) {
  unsigned u = __float_as_uint(x);
  return (unsigned short)((u + 0x7fffu + ((u >> 16) & 1u)) >> 16);
}

// monotone float <-> uint (order-preserving incl. negatives)
__device__ __forceinline__ unsigned encf(float f) {
  unsigned b = __float_as_uint(f);
  return (b >> 31) ? ~b : (b | 0x80000000u);
}
__device__ __forceinline__ float decf(unsigned u) {
  return __uint_as_float((u >> 31) ? (u ^ 0x80000000u) : ~u);
}

// ---------------------------------------------------------------------------
__global__ __launch_bounds__(256) void init_kernel(unsigned* __restrict__ misc,
                                                   unsigned* __restrict__ rowMinU,
                                                   unsigned long long* __restrict__ pKey) {
  int i = blockIdx.x * 256 + threadIdx.x;   // 32768
  if (i < 16) misc[i] = 0u;
  rowMinU[i] = 0xFFFFFFFFu;
  pKey[i] = ~0ull;
}

// ---------------------------------------------------------------------------
// prep: bf16 h-planes + squared norms + neMax.
// ---------------------------------------------------------------------------
__global__ __launch_bounds__(256) void prep_kernel(const float* __restrict__ x,
                                                   const float* __restrict__ embed,
                                                   unsigned short* __restrict__ A_h,
                                                   unsigned short* __restrict__ E_h,
                                                   float* __restrict__ x2,
                                                   float* __restrict__ nx,
                                                   float* __restrict__ e2,
                                                   unsigned* __restrict__ misc) {
  int wid  = threadIdx.x >> 6;
  int lane = threadIdx.x & 63;
  int rid  = blockIdx.x * 4 + wid;   // 0..40959
  const float* src;
  unsigned short* dst;
  if (rid < NROWS) { src = x + (size_t)rid * D;               dst = A_h + (size_t)rid * D; }
  else             { src = embed + (size_t)(rid - NROWS) * D; dst = E_h + (size_t)(rid - NROWS) * D; }
  float4 v = *(const float4*)(src + lane * 4);
  ushort4 hv = make_ushort4(bf16rn(v.x), bf16rn(v.y), bf16rn(v.z), bf16rn(v.w));
  *(ushort4*)(dst + lane * 4) = hv;
  float p = v.x * v.x + v.y * v.y + v.z * v.z + v.w * v.w;
  #pragma unroll
  for (int off = 32; off > 0; off >>= 1) p += __shfl_down(p, off);
  if (lane == 0) {
    float n = sqrtf(p);
    if (rid < NROWS) { x2[rid] = p; nx[rid] = n; }
    else { e2[rid - NROWS] = p; atomicMax(&misc[2], __float_as_uint(n)); }
  }
}

// ---------------------------------------------------------------------------
// 256x128-tile GEMM, A register-resident (af[2][16] per wave, direct from
// global), B double-buffered in LDS with rotation swizzle:
//   LDS[row][k-byte kb] stored at row*512 + ((kb + row*16) & 511)
// -> every consecutive-8-lane group of the frag ds_read_b128 covers all 32
// banks exactly once. 2-phase: STAGE(next) issued before compute(cur), one
// barrier per chunk (implicit vmcnt drain hides load latency under MFMAs).
// MODE0: per-row min of q = e2 - 2*xe.  MODE1: collect q <= rowMin + margin.
// ---------------------------------------------------------------------------
template<int MODE>
__global__ __launch_bounds__(512, 1) void gemm_pass(
    const unsigned short* __restrict__ A_h,
    const unsigned short* __restrict__ E_h,
    const float* __restrict__ e2g,
    const float* __restrict__ nxg,
    const unsigned* __restrict__ miscR,
    unsigned* __restrict__ rowMinU,
    unsigned* __restrict__ cand,        // NBLK*LQ segmented + overflow tail
    unsigned* __restrict__ blkCnt,
    unsigned* __restrict__ ovCnt,       // &misc[1]
    unsigned OVCAP) {
  __shared__ __align__(16) char Bbuf0[65536];
  __shared__ __align__(16) char Bbuf1[65536];
  __shared__ __align__(16) float e2s[SPLC];    // 8KB, whole split
  __shared__ unsigned lbuf[MODE ? LQ : 1];
  __shared__ unsigned lcnt;

  const int tid  = threadIdx.x;
  const int lane = tid & 63;
  const int wave = tid >> 6;            // 0..7
  const int wm = wave >> 1;             // 0..3  row group (64 rows)
  const int wn = wave & 1;              // 0..1  col group (64 cols)
  const int l31 = lane & 31;
  const int hi16 = (lane >> 5) << 4;
  const int lh4  = (lane >> 5) << 2;
  const int rowBase = blockIdx.x * BM;
  const int split   = blockIdx.y;
  const int seg     = blockIdx.y * 128 + blockIdx.x;

  // ---- B staging (rotation swizzle; dest linear, source wrapped-in-row) ----
  auto STAGE = [&](char* buf, int cBase) {
    #pragma unroll
    for (int i = 0; i < 8; i++) {
      int q   = i * 512 + tid;               // 16B slot 0..4095
      int row = q >> 5;                      // 0..127 (code within chunk)
      int kb  = (((q & 31) << 4) - (row << 4)) & 511;   // logical k-byte
      gload16((const char*)E_h + (((size_t)(cBase + row)) << 9) + kb,
              buf + ((q & ~63) << 4));
    }
  };

  // ---- prologue: stage chunk 0 + e2 slab, then A frags direct to regs ----
  STAGE(Bbuf0, split * SPLC);
  gload16((const char*)e2g + (size_t)split * SPLC * 4 + tid * 16,
          (char*)e2s + ((tid & ~63) << 4));

  bf16x8 af[2][16];
  #pragma unroll
  for (int f = 0; f < 2; f++) {
    const char* abase = (const char*)A_h
        + (((size_t)(rowBase + wm * 64 + f * 32 + l31)) << 9) + hi16;
    #pragma unroll
    for (int ks = 0; ks < 16; ks++)
      af[f][ks] = *(const bf16x8*)(abase + ks * 32);
  }

  // B fragment address components (rotation)
  int bbase[2], brot[2];
  #pragma unroll
  for (int g = 0; g < 2; g++) {
    int rowB = wn * 64 + g * 32 + l31;
    bbase[g] = rowB << 9;
    brot[g]  = ((rowB << 4) + hi16) & 511;
  }

  float state[2][16];   // MODE0: running min q; MODE1: thresholds
  if (MODE == 0) {
    #pragma unroll
    for (int fm = 0; fm < 2; fm++)
      #pragma unroll
      for (int rg = 0; rg < 16; rg++) state[fm][rg] = INFINITY;
  } else {
    float neMaxF = __uint_as_float(miscR[2]);
    #pragma unroll
    for (int fm = 0; fm < 2; fm++)
      #pragma unroll
      for (int rg = 0; rg < 16; rg++) {
        int row = rowBase + wm * 64 + fm * 32 + ((rg & 3) + 8 * (rg >> 2)) + lh4;
        state[fm][rg] = decf(rowMinU[row]) + fmaf(MARG_COEF * nxg[row], neMaxF, MARG_ABS);
      }
    if (tid == 0) lcnt = 0;
  }

  __syncthreads();   // chunk-0 stage + e2 slab landed (implicit vmcnt drain)

  #pragma unroll 2
  for (int cc = 0; cc < NCHUNK; ++cc) {
    char* cb = (cc & 1) ? Bbuf1 : Bbuf0;
    char* nb = (cc & 1) ? Bbuf0 : Bbuf1;
    if (cc < NCHUNK - 1) STAGE(nb, split * SPLC + (cc + 1) * BN);

    f32x16 acc[2][2];
    #pragma unroll
    for (int i = 0; i < 2; i++)
      #pragma unroll
      for (int j = 0; j < 2; j++) acc[i][j] = (f32x16)(0.0f);

    #pragma unroll
    for (int ks = 0; ks < 16; ks++) {
      bf16x8 b0 = *(const bf16x8*)(cb + bbase[0] + (((ks << 5) + brot[0]) & 511));
      bf16x8 b1 = *(const bf16x8*)(cb + bbase[1] + (((ks << 5) + brot[1]) & 511));
      acc[0][0] = __builtin_amdgcn_mfma_f32_32x32x16_bf16(af[0][ks], b0, acc[0][0], 0, 0, 0);
      acc[1][0] = __builtin_amdgcn_mfma_f32_32x32x16_bf16(af[1][ks], b0, acc[1][0], 0, 0, 0);
      acc[0][1] = __builtin_amdgcn_mfma_f32_32x32x16_bf16(af[0][ks], b1, acc[0][1], 0, 0, 0);
      acc[1][1] = __builtin_amdgcn_mfma_f32_32x32x16_bf16(af[1][ks], b1, acc[1][1], 0, 0, 0);
    }

    // epilogue: q = e2 - 2*xe  (C/D map: row=(rg&3)+8*(rg>>2)+lh4, col=l31)
    if (MODE == 0) {
      #pragma unroll
      for (int g = 0; g < 2; g++) {
        float e2c = e2s[cc * BN + wn * 64 + g * 32 + l31];
        #pragma unroll
        for (int fm = 0; fm < 2; fm++)
          #pragma unroll
          for (int rg = 0; rg < 16; rg++)
            state[fm][rg] = fminf(state[fm][rg], fmaf(acc[fm][g][rg], -2.0f, e2c));
      }
    } else {
      const int cBase = split * SPLC + cc * BN;
      #pragma unroll
      for (int g = 0; g < 2; g++) {
        int col = cBase + wn * 64 + g * 32 + l31;
        float e2c = e2s[cc * BN + wn * 64 + g * 32 + l31];
        #pragma unroll
        for (int fm = 0; fm < 2; fm++)
          #pragma unroll
          for (int rg = 0; rg < 16; rg++) {
            float q = fmaf(acc[fm][g][rg], -2.0f, e2c);
            if (q <= state[fm][rg]) {
              int row = rowBase + wm * 64 + fm * 32 + ((rg & 3) + 8 * (rg >> 2)) + lh4;
              unsigned en = (unsigned)((row << 13) | col);
              unsigned p = atomicAdd(&lcnt, 1u);
              if (p < LQ) lbuf[p] = en;
              else { unsigned gp = atomicAdd(ovCnt, 1u);
                     if (gp < OVCAP) cand[(size_t)NBLK * LQ + gp] = en; }
            }
          }
      }
    }

    __syncthreads();   // drains next-chunk stage (vmcnt 0) + guards buffer swap
  }

  if (MODE == 0) {
    #pragma unroll
    for (int fm = 0; fm < 2; fm++)
      #pragma unroll
      for (int rg = 0; rg < 16; rg++) {
        float v = state[fm][rg];
        #pragma unroll
        for (int off = 1; off < 32; off <<= 1) v = fminf(v, __shfl_xor(v, off));
        if (l31 == 0) {
          int row = rowBase + wm * 64 + fm * 32 + ((rg & 3) + 8 * (rg >> 2)) + lh4;
          atomicMin(&rowMinU[row], encf(v));
        }
      }
  } else {
    unsigned n = lcnt; if (n > LQ) n = LQ;
    for (unsigned i = tid; i < n; i += 512) cand[(size_t)seg * LQ + i] = lbuf[i];
    if (tid == 0) blkCnt[seg] = n;
  }
}

// ---------------------------------------------------------------------------
// refine: 16-lane groups, fp64 dot, exact ref combine, u64 atomicMin key.
// ---------------------------------------------------------------------------
__global__ __launch_bounds__(256) void refine_kernel(const float* __restrict__ x,
                                                     const float* __restrict__ embed,
                                                     const float* __restrict__ x2g,
                                                     const float* __restrict__ e2g,
                                                     const unsigned* __restrict__ blkCnt,
                                                     const unsigned* __restrict__ cand,
                                                     const unsigned* __restrict__ miscR,
                                                     unsigned long long* __restrict__ pKey,
                                                     unsigned OVCAP) {
  const int tid = threadIdx.x;
  const int l16 = tid & 15;
  const int gid = tid >> 4;

  auto doItem = [&](unsigned pk) {
    int row = (int)(pk >> 13), col = (int)(pk & 8191u);
    double s = 0.0;
    #pragma unroll
    for (int p = 0; p < 4; p++) {
      float4 xv = *(const float4*)&x[(size_t)row * D + p * 64 + l16 * 4];
      float4 ev = *(const float4*)&embed[(size_t)col * D + p * 64 + l16 * 4];
      s = fma((double)xv.x, (double)ev.x, s);
      s = fma((double)xv.y, (double)ev.y, s);
      s = fma((double)xv.z, (double)ev.z, s);
      s = fma((double)xv.w, (double)ev.w, s);
    }
    #pragma unroll
    for (int off = 1; off < 16; off <<= 1) s += __shfl_xor(s, off);
    if (l16 == 0) {
      float xef = (float)s;
      float ss  = __fadd_rn(x2g[row], e2g[col]);
      float d2  = __fsub_rn(ss, __fmul_rn(2.0f, xef));
      d2 = fmaxf(d2, 0.0f);
      float sq = sqrtf(d2);
      unsigned long long key =
          ((unsigned long long)__float_as_uint(sq) << 32) | (unsigned)col;
      atomicMin(pKey + row, key);
    }
  };

  unsigned seg = blockIdx.x;             // NBLK blocks
  unsigned n = blkCnt[seg]; if (n > LQ) n = LQ;
  const unsigned* segp = cand + (size_t)seg * LQ;
  for (unsigned i = gid; i < n; i += 16) doItem(segp[i]);

  unsigned ov = miscR[1]; if (ov > OVCAP) ov = OVCAP;
  const unsigned* ovp = cand + (size_t)NBLK * LQ;
  for (unsigned i = blockIdx.x * 16 + gid; i < ov; i += NBLK * 16) doItem(ovp[i]);
}

// ---------------------------------------------------------------------------
// finalize: gather codes + write index as float.
// ---------------------------------------------------------------------------
__global__ __launch_bounds__(256) void final_kernel(const float* __restrict__ embed,
                                                    const unsigned long long* __restrict__ pKey,
                                                    float* __restrict__ outQ,
                                                    float* __restrict__ indF) {
  int wid  = threadIdx.x >> 6;
  int lane = threadIdx.x & 63;
  int row  = blockIdx.x * 4 + wid;
  unsigned long long k = pKey[row];
  int idx = (int)(k & 8191ull);
  float4 v = *(const float4*)&embed[(size_t)idx * D + lane * 4];
  *(float4*)&outQ[(size_t)row * D + lane * 4] = v;
  if (lane == 0) indF[row] = (float)idx;
}

// ===========================================================================
// Fallback fp32 path (round-1, proven) — used if ws_size < WS_NEED4.
// ===========================================================================
#define BM_F 128
#define BN_F 128
#define BK_F 32
#define NSPLIT_F 4
#define SPLIT_CF (CODES / NSPLIT_F)

__global__ __launch_bounds__(256) void sq_kernel(const float* __restrict__ x,
                                                 const float* __restrict__ embed,
                                                 float* __restrict__ x2,
                                                 float* __restrict__ e2) {
  int wid  = threadIdx.x >> 6;
  int lane = threadIdx.x & 63;
  int rid  = blockIdx.x * 4 + wid;
  const float* base = (rid < NROWS) ? (x + (size_t)rid * D)
                                    : (embed + (size_t)(rid - NROWS) * D);
  float4 v = *(const float4*)(base + lane * 4);
  float p = v.x * v.x + v.y * v.y + v.z * v.z + v.w * v.w;
  #pragma unroll
  for (int off = 32; off > 0; off >>= 1) p += __shfl_down(p, off);
  if (lane == 0) {
    if (rid < NROWS) x2[rid] = p;
    else             e2[rid - NROWS] = p;
  }
}

__global__ __launch_bounds__(256) void argmin_f32_kernel(const float* __restrict__ x,
                                                         const float* __restrict__ embed,
                                                         const float* __restrict__ x2,
                                                         const float* __restrict__ e2,
                                                         float* __restrict__ pVal,
                                                         int* __restrict__ pIdx) {
  __shared__ float As[BK_F][BM_F];
  __shared__ float Bs[BK_F][BN_F];
  const int tid = threadIdx.x;
  const int ty = tid >> 4, tx = tid & 15;
  const int rowBase = blockIdx.x * BM_F;
  const int split = blockIdx.y;
  const int r0 = ty * 8, c0 = tx * 8;
  float bestV[8]; int bestI[8];
  #pragma unroll
  for (int i = 0; i < 8; i++) { bestV[i] = -INFINITY; bestI[i] = 0; }
  float x2r[8];
  #pragma unroll
  for (int i = 0; i < 8; i++) x2r[i] = x2[rowBase + r0 + i];
  for (int chunk = 0; chunk < SPLIT_CF / BN_F; ++chunk) {
    const int cBase = split * SPLIT_CF + chunk * BN_F;
    float acc[8][8];
    #pragma unroll
    for (int i = 0; i < 8; i++)
      #pragma unroll
      for (int j = 0; j < 8; j++) acc[i][j] = 0.0f;
    for (int kb = 0; kb < D / BK_F; ++kb) {
      #pragma unroll
      for (int i = 0; i < 4; i++) {
        int f4 = tid + i * 256;
        int rr = f4 >> 3, k4 = f4 & 7;
        float4 va = *(const float4*)&x[(size_t)(rowBase + rr) * D + kb * BK_F + k4 * 4];
        As[k4 * 4 + 0][rr] = va.x; As[k4 * 4 + 1][rr] = va.y;
        As[k4 * 4 + 2][rr] = va.z; As[k4 * 4 + 3][rr] = va.w;
        float4 vb = *(const float4*)&embed[(size_t)(cBase + rr) * D + kb * BK_F + k4 * 4];
        Bs[k4 * 4 + 0][rr] = vb.x; Bs[k4 * 4 + 1][rr] = vb.y;
        Bs[k4 * 4 + 2][rr] = vb.z; Bs[k4 * 4 + 3][rr] = vb.w;
      }
      __syncthreads();
      #pragma unroll 8
      for (int kk = 0; kk < BK_F; kk++) {
        float a[8], b[8];
        *(float4*)&a[0] = *(const float4*)&As[kk][r0];
        *(float4*)&a[4] = *(const float4*)&As[kk][r0 + 4];
        *(float4*)&b[0] = *(const float4*)&Bs[kk][c0];
        *(float4*)&b[4] = *(const float4*)&Bs[kk][c0 + 4];
        #pragma unroll
        for (int i = 0; i < 8; i++)
          #pragma unroll
          for (int j = 0; j < 8; j++)
            acc[i][j] = fmaf(a[i], b[j], acc[i][j]);
      }
      __syncthreads();
    }
    #pragma unroll
    for (int j = 0; j < 8; j++) {
      int c = cBase + c0 + j;
      float e2c = e2[c];
      #pragma unroll
      for (int i = 0; i < 8; i++) {
        float s  = __fadd_rn(x2r[i], e2c);
        float u  = __fmul_rn(2.0f, acc[i][j]);
        float d2 = fmaxf(__fsub_rn(s, u), 0.0f);
        float dist = -sqrtf(d2);
        if (dist > bestV[i]) { bestV[i] = dist; bestI[i] = c; }
      }
    }
  }
  __syncthreads();
  float* Vl = &As[0][0];
  int*   Il = (int*)&Bs[0][0];
  #pragma unroll
  for (int i = 0; i < 8; i++) {
    Vl[(ty * 16 + tx) * 8 + i] = bestV[i];
    Il[(ty * 16 + tx) * 8 + i] = bestI[i];
  }
  __syncthreads();
  if (tid < BM_F) {
    int rr = tid, tyr = rr >> 3, ii = rr & 7;
    float bv = -INFINITY; int bi = 0;
    #pragma unroll
    for (int t = 0; t < 16; t++) {
      float v = Vl[(tyr * 16 + t) * 8 + ii];
      int  iv = Il[(tyr * 16 + t) * 8 + ii];
      if (v > bv || (v == bv && iv < bi)) { bv = v; bi = iv; }
    }
    pVal[split * NROWS + rowBase + rr] = bv;
    pIdx[split * NROWS + rowBase + rr] = bi;
  }
}

__global__ __launch_bounds__(256) void merge_f32_kernel(const float* __restrict__ pVal,
                                                        const int* __restrict__ pIdx,
                                                        float* __restrict__ indF) {
  int row = blockIdx.x * 256 + threadIdx.x;
  if (row >= NROWS) return;
  float bv = -INFINITY; int bi = 0;
  #pragma unroll
  for (int s = 0; s < NSPLIT_F; s++) {
    float v = pVal[s * NROWS + row];
    int  iv = pIdx[s * NROWS + row];
    if (v > bv || (v == bv && iv < bi)) { bv = v; bi = iv; }
  }
  indF[row] = (float)bi;
}

__global__ __launch_bounds__(256) void gather_f32_kernel(const float* __restrict__ embed,
                                                         const float* __restrict__ indF,
                                                         float* __restrict__ outQ) {
  int wid = threadIdx.x >> 6, lane = threadIdx.x & 63;
  int row = blockIdx.x * 4 + wid;
  int idx = (int)indF[row];
  float4 v = *(const float4*)&embed[(size_t)idx * D + lane * 4];
  *(float4*)&outQ[(size_t)row * D + lane * 4] = v;
}

// ---------------------------------------------------------------------------
extern "C" void kernel_launch(void* const* d_in, const int* in_sizes, int n_in,
                              void* d_out, int out_size, void* d_ws, size_t ws_size,
                              hipStream_t stream) {
  const float* x     = (const float*)d_in[0];
  const float* embed = (const float*)d_in[1];
  float* o = (float*)d_out;

  if (ws_size >= WS_NEED4) {
    char* w = (char*)d_ws;
    unsigned short* A_h = (unsigned short*)(w + OFF_AH);
    float* x2 = (float*)(w + OFF_X2);
    float* nx = (float*)(w + OFF_NX);
    float* e2 = (float*)(w + OFF_E2);
    unsigned* rowMinU = (unsigned*)(w + OFF_RM);
    unsigned long long* pKey = (unsigned long long*)(w + OFF_PK);
    unsigned* misc = (unsigned*)(w + OFF_MISC);
    unsigned* blkCnt = (unsigned*)(w + OFF_BCNT);
    unsigned* cand = (unsigned*)(w + OFF_CAND);
    unsigned capN  = (unsigned)((ws_size - OFF_CAND) / 4ull);
    unsigned OVCAP = capN - (unsigned)(NBLK * LQ);

    unsigned short* E_h = (unsigned short*)o;      // 4MB scratch in quantize region
    float* indF = o + QOFF;

    init_kernel<<<128, 256, 0, stream>>>(misc, rowMinU, pKey);
    prep_kernel<<<(NROWS + CODES) / 4, 256, 0, stream>>>(x, embed, A_h, E_h, x2, nx, e2, misc);
    dim3 gridC(NROWS / BM, NSPL);
    gemm_pass<0><<<gridC, 512, 0, stream>>>(A_h, E_h, e2, nx, misc, rowMinU,
                                            cand, blkCnt, &misc[1], OVCAP);
    gemm_pass<1><<<gridC, 512, 0, stream>>>(A_h, E_h, e2, nx, misc, rowMinU,
                                            cand, blkCnt, &misc[1], OVCAP);
    refine_kernel<<<NBLK, 256, 0, stream>>>(x, embed, x2, e2, blkCnt, cand, misc,
                                            pKey, OVCAP);
    final_kernel<<<NROWS / 4, 256, 0, stream>>>(embed, pKey, o, indF);
  } else {
    // ---- fp32 fallback ----
    float* x2   = o;
    float* e2   = o + 32768;
    float* pVal = o + 65536;
    int*   pIdx = (int*)(o + 196608);
    float* indF = o + QOFF;
    sq_kernel<<<(NROWS + CODES) / 4, 256, 0, stream>>>(x, embed, x2, e2);
    dim3 gridB(NROWS / BM_F, NSPLIT_F);
    argmin_f32_kernel<<<gridB, 256, 0, stream>>>(x, embed, x2, e2, pVal, pIdx);
    merge_f32_kernel<<<NROWS / 256, 256, 0, stream>>>(pVal, pIdx, indF);
    gather_f32_kernel<<<NROWS / 4, 256, 0, stream>>>(embed, indF, o);
  }
}

// Round 8
// 498.366 us; speedup vs baseline: 1.6844x; 1.6844x over previous
//
#include <hip/hip_runtime.h>
#include <math.h>

#define D       256
#define NROWS   32768      // 8 * 4096
#define CODES   8192
#define QOFF    8388608    // index output offset (floats) in d_out

// ---------------- coarse GEMM config ----------------
#define BM      128
#define BN      128
#define NSPL    4
#define SPLC    (CODES / NSPL)    // 2048
#define NCHUNK  (SPLC / BN)       // 16
#define NSTEP   (NCHUNK * 4)      // 64 kb-steps (BK=64)
#define NBLK    1024              // 256 * NSPL
#define LQ      2048              // LDS candidate buffer entries (pass 2)

// rigorous collect margin (2M): 2*2*(2u+u^2)*||x||*||e||max, u=2^-9 (bf16 rn)
#define MARG_COEF 0.016f
#define MARG_ABS  0.10f

// ---------------- ws layout (bytes) ----------------
#define OFF_AH    0ull               // 32768*512 = 16777216
#define OFF_X2    16777216ull
#define OFF_NX    16908288ull
#define OFF_E2    17039360ull
#define OFF_RM    17072128ull        // 32768*4 (monotone-encoded float bits)
#define OFF_PK    17203200ull        // 32768*8
#define OFF_MISC  17465344ull        // [1]=ovCnt, [2]=neMaxBits
#define OFF_BCNT  17465600ull        // 1024*4
#define OFF_CAND  17469696ull        // 4B entries: NBLK*LQ segmented + overflow
#define WS_NEED3  30052608ull        // OFF_CAND + 8MB segs + 4MB overflow

typedef __attribute__((ext_vector_type(8)))  short bf16x8;
typedef __attribute__((ext_vector_type(16))) float f32x16;

// Involutive swizzle for 128B LDS rows: bits 6:4 ^= row bits 2:0 (addr 9:7).
__device__ __forceinline__ int SWK(int b) { return b ^ (((b >> 7) & 7) << 4); }

__device__ __forceinline__ void gload16(const void* g, void* l) {
  __builtin_amdgcn_global_load_lds(
      (const __attribute__((address_space(1))) unsigned int*)g,
      (__attribute__((address_space(3))) unsigned int*)l, 16, 0, 0);
}

__device__ __forceinline__ unsigned short bf16rn(float x) {
  unsigned u = __float_as_uint(x);
  return (unsigned short)((u + 0x7fffu + ((u >> 16) & 1u)) >> 16);
}

// monotone float <-> uint (order-preserving incl. negatives)
__device__ __forceinline__ unsigned encf(float f) {
  unsigned b = __float_as_uint(f);
  return (b >> 31) ? ~b : (b | 0x80000000u);
}
__device__ __forceinline__ float decf(unsigned u) {
  return __uint_as_float((u >> 31) ? (u ^ 0x80000000u) : ~u);
}

// ---------------------------------------------------------------------------
__global__ __launch_bounds__(256) void init_kernel(unsigned* __restrict__ misc,
                                                   unsigned* __restrict__ rowMinU,
                                                   unsigned long long* __restrict__ pKey) {
  int i = blockIdx.x * 256 + threadIdx.x;   // 32768
  if (i < 16) misc[i] = 0u;
  rowMinU[i] = 0xFFFFFFFFu;
  pKey[i] = ~0ull;
}

// ---------------------------------------------------------------------------
// prep: bf16 h-planes + squared norms + neMax.
// ---------------------------------------------------------------------------
__global__ __launch_bounds__(256) void prep_kernel(const float* __restrict__ x,
                                                   const float* __restrict__ embed,
                                                   unsigned short* __restrict__ A_h,
                                                   unsigned short* __restrict__ E_h,
                                                   float* __restrict__ x2,
                                                   float* __restrict__ nx,
                                                   float* __restrict__ e2,
                                                   unsigned* __restrict__ misc) {
  int wid  = threadIdx.x >> 6;
  int lane = threadIdx.x & 63;
  int rid  = blockIdx.x * 4 + wid;   // 0..40959
  const float* src;
  unsigned short* dst;
  if (rid < NROWS) { src = x + (size_t)rid * D;               dst = A_h + (size_t)rid * D; }
  else             { src = embed + (size_t)(rid - NROWS) * D; dst = E_h + (size_t)(rid - NROWS) * D; }
  float4 v = *(const float4*)(src + lane * 4);
  ushort4 hv = make_ushort4(bf16rn(v.x), bf16rn(v.y), bf16rn(v.z), bf16rn(v.w));
  *(ushort4*)(dst + lane * 4) = hv;
  float p = v.x * v.x + v.y * v.y + v.z * v.z + v.w * v.w;
  #pragma unroll
  for (int off = 32; off > 0; off >>= 1) p += __shfl_down(p, off);
  if (lane == 0) {
    float n = sqrtf(p);
    if (rid < NROWS) { x2[rid] = p; nx[rid] = n; }
    else { e2[rid - NROWS] = p; atomicMax(&misc[2], __float_as_uint(n)); }
  }
}

// ---------------------------------------------------------------------------
// Double-buffered 2-phase GEMM (round-5 engine + T3-minimum schedule):
// per kb-step: issue STAGE(next) -> compute(cur) -> [chunk-end epilogue]
// -> ONE __syncthreads (its vmcnt drain lands after a full compute phase).
// Tile 128x128, BK=64, 4 waves (2x2), 2x2 frags of mfma_f32_32x32x16_bf16.
// MODE0: per-row min of q = e2 - 2*xe.  MODE1: collect q <= rowMin + margin.
// Identical engine => bit-identical q between passes.
// ---------------------------------------------------------------------------
template<int MODE>
__global__ __launch_bounds__(256, 2) void gemm_pass(
    const unsigned short* __restrict__ A_h,
    const unsigned short* __restrict__ E_h,
    const float* __restrict__ e2g,
    const float* __restrict__ nxg,
    const unsigned* __restrict__ miscR,
    unsigned* __restrict__ rowMinU,
    unsigned* __restrict__ cand,        // NBLK*LQ segmented + overflow tail
    unsigned* __restrict__ blkCnt,
    unsigned* __restrict__ ovCnt,       // &misc[1]
    unsigned OVCAP) {
  __shared__ __align__(16) char As0[16384];
  __shared__ __align__(16) char As1[16384];
  __shared__ __align__(16) char Bs0[16384];
  __shared__ __align__(16) char Bs1[16384];
  __shared__ unsigned lbuf[MODE ? LQ : 1];
  __shared__ unsigned lcnt;

  const int tid  = threadIdx.x;
  const int lane = tid & 63;
  const int wave = tid >> 6;
  const int wm = wave >> 1, wn = wave & 1;
  const int l31 = lane & 31;
  const int lh4 = (lane >> 5) << 2;
  const int rowBase = blockIdx.x * BM;
  const int split   = blockIdx.y;
  const int seg     = blockIdx.y * 256 + blockIdx.x;

  // fragment LDS byte offsets (row stride 128B, swizzled)
  int swA[2][4], swB[2][4];
  #pragma unroll
  for (int f = 0; f < 2; f++)
    #pragma unroll
    for (int ks = 0; ks < 4; ks++) {
      int byt = ks * 32 + (lane >> 5) * 16;
      swA[f][ks] = SWK(((wm * 64 + f * 32 + l31) << 7) + byt);
      swB[f][ks] = SWK(((wn * 64 + f * 32 + l31) << 7) + byt);
    }

  // staging slots: 4 gload16 each for A and B per kb step (16KB tiles)
  int stRow[4], stCo[4], stDst[4];
  #pragma unroll
  for (int i = 0; i < 4; i++) {
    int q = i * 256 + tid;          // 0..1023 16B-slot
    int u = SWK(q << 4);            // logical byte (involution)
    stRow[i] = u >> 7;
    stCo[i]  = u & 127;
    stDst[i] = (q & ~63) << 4;      // wave-uniform base
  }

  auto STAGE = [&](char* Ad, char* Bd, int s) {
    int cc = s >> 2, kb = s & 3;
    const int cBase = split * SPLC + cc * BN;
    #pragma unroll
    for (int i = 0; i < 4; i++) {
      gload16((const char*)A_h + (((size_t)(rowBase + stRow[i])) << 9) + (kb << 7) + stCo[i],
              Ad + stDst[i]);
      gload16((const char*)E_h + (((size_t)(cBase + stRow[i])) << 9) + (kb << 7) + stCo[i],
              Bd + stDst[i]);
    }
  };

  // ---- prologue: stage step 0; state init overlaps the loads ----
  STAGE(As0, Bs0, 0);
  if (MODE == 1 && tid == 0) lcnt = 0;

  float state[2][16];   // MODE0: running min q; MODE1: thresholds
  if (MODE == 0) {
    #pragma unroll
    for (int fm = 0; fm < 2; fm++)
      #pragma unroll
      for (int rg = 0; rg < 16; rg++) state[fm][rg] = INFINITY;
  } else {
    float neMaxF = __uint_as_float(miscR[2]);
    #pragma unroll
    for (int fm = 0; fm < 2; fm++)
      #pragma unroll
      for (int rg = 0; rg < 16; rg++) {
        int row = rowBase + wm * 64 + fm * 32 + ((rg & 3) + 8 * (rg >> 2)) + lh4;
        state[fm][rg] = decf(rowMinU[row]) + fmaf(MARG_COEF * nxg[row], neMaxF, MARG_ABS);
      }
  }

  f32x16 acc[2][2];
  #pragma unroll
  for (int i = 0; i < 2; i++)
    #pragma unroll
    for (int j = 0; j < 2; j++) acc[i][j] = (f32x16)(0.0f);

  __syncthreads();   // step-0 stage landed

  for (int s = 0; s < NSTEP; ++s) {
    char* Ac = (s & 1) ? As1 : As0;
    char* Bc = (s & 1) ? Bs1 : Bs0;
    if (s + 1 < NSTEP) STAGE((s & 1) ? As0 : As1, (s & 1) ? Bs0 : Bs1, s + 1);

    #pragma unroll
    for (int ks = 0; ks < 4; ++ks) {
      bf16x8 a0 = *(const bf16x8*)(Ac + swA[0][ks]);
      bf16x8 a1 = *(const bf16x8*)(Ac + swA[1][ks]);
      bf16x8 b0 = *(const bf16x8*)(Bc + swB[0][ks]);
      bf16x8 b1 = *(const bf16x8*)(Bc + swB[1][ks]);
      acc[0][0] = __builtin_amdgcn_mfma_f32_32x32x16_bf16(a0, b0, acc[0][0], 0, 0, 0);
      acc[1][0] = __builtin_amdgcn_mfma_f32_32x32x16_bf16(a1, b0, acc[1][0], 0, 0, 0);
      acc[0][1] = __builtin_amdgcn_mfma_f32_32x32x16_bf16(a0, b1, acc[0][1], 0, 0, 0);
      acc[1][1] = __builtin_amdgcn_mfma_f32_32x32x16_bf16(a1, b1, acc[1][1], 0, 0, 0);
    }

    if ((s & 3) == 3) {
      // chunk epilogue: q = e2 - 2*xe (C/D map: row=(rg&3)+8*(rg>>2)+lh4, col=l31)
      const int cc = s >> 2;
      const int cBase = split * SPLC + cc * BN;
      if (MODE == 0) {
        #pragma unroll
        for (int g = 0; g < 2; g++) {
          float e2c = e2g[cBase + wn * 64 + g * 32 + l31];
          #pragma unroll
          for (int fm = 0; fm < 2; fm++)
            #pragma unroll
            for (int rg = 0; rg < 16; rg++)
              state[fm][rg] = fminf(state[fm][rg], fmaf(acc[fm][g][rg], -2.0f, e2c));
        }
      } else {
        #pragma unroll
        for (int g = 0; g < 2; g++) {
          int col = cBase + wn * 64 + g * 32 + l31;
          float e2c = e2g[col];
          #pragma unroll
          for (int fm = 0; fm < 2; fm++)
            #pragma unroll
            for (int rg = 0; rg < 16; rg++) {
              float q = fmaf(acc[fm][g][rg], -2.0f, e2c);
              if (q <= state[fm][rg]) {
                int row = rowBase + wm * 64 + fm * 32 + ((rg & 3) + 8 * (rg >> 2)) + lh4;
                unsigned en = (unsigned)((row << 13) | col);
                unsigned p = atomicAdd(&lcnt, 1u);
                if (p < LQ) lbuf[p] = en;
                else { unsigned gp = atomicAdd(ovCnt, 1u);
                       if (gp < OVCAP) cand[(size_t)NBLK * LQ + gp] = en; }
              }
            }
        }
      }
      #pragma unroll
      for (int i = 0; i < 2; i++)
        #pragma unroll
        for (int j = 0; j < 2; j++) acc[i][j] = (f32x16)(0.0f);
    }

    __syncthreads();   // drains next-step stage; guards buffer swap
  }

  if (MODE == 0) {
    #pragma unroll
    for (int fm = 0; fm < 2; fm++)
      #pragma unroll
      for (int rg = 0; rg < 16; rg++) {
        float v = state[fm][rg];
        #pragma unroll
        for (int off = 1; off < 32; off <<= 1) v = fminf(v, __shfl_xor(v, off));
        if (l31 == 0) {
          int row = rowBase + wm * 64 + fm * 32 + ((rg & 3) + 8 * (rg >> 2)) + lh4;
          atomicMin(&rowMinU[row], encf(v));
        }
      }
  } else {
    unsigned n = lcnt; if (n > LQ) n = LQ;
    for (unsigned i = tid; i < n; i += 256) cand[(size_t)seg * LQ + i] = lbuf[i];
    if (tid == 0) blkCnt[seg] = n;
  }
}

// ---------------------------------------------------------------------------
// refine: 16-lane groups, fp64 dot, exact ref combine, u64 atomicMin key.
// ---------------------------------------------------------------------------
__global__ __launch_bounds__(256) void refine_kernel(const float* __restrict__ x,
                                                     const float* __restrict__ embed,
                                                     const float* __restrict__ x2g,
                                                     const float* __restrict__ e2g,
                                                     const unsigned* __restrict__ blkCnt,
                                                     const unsigned* __restrict__ cand,
                                                     const unsigned* __restrict__ miscR,
                                                     unsigned long long* __restrict__ pKey,
                                                     unsigned OVCAP) {
  const int tid = threadIdx.x;
  const int l16 = tid & 15;
  const int gid = tid >> 4;

  auto doItem = [&](unsigned pk) {
    int row = (int)(pk >> 13), col = (int)(pk & 8191u);
    double s = 0.0;
    #pragma unroll
    for (int p = 0; p < 4; p++) {
      float4 xv = *(const float4*)&x[(size_t)row * D + p * 64 + l16 * 4];
      float4 ev = *(const float4*)&embed[(size_t)col * D + p * 64 + l16 * 4];
      s = fma((double)xv.x, (double)ev.x, s);
      s = fma((double)xv.y, (double)ev.y, s);
      s = fma((double)xv.z, (double)ev.z, s);
      s = fma((double)xv.w, (double)ev.w, s);
    }
    #pragma unroll
    for (int off = 1; off < 16; off <<= 1) s += __shfl_xor(s, off);
    if (l16 == 0) {
      float xef = (float)s;
      float ss  = __fadd_rn(x2g[row], e2g[col]);
      float d2  = __fsub_rn(ss, __fmul_rn(2.0f, xef));
      d2 = fmaxf(d2, 0.0f);
      float sq = sqrtf(d2);
      unsigned long long key =
          ((unsigned long long)__float_as_uint(sq) << 32) | (unsigned)col;
      atomicMin(pKey + row, key);
    }
  };

  unsigned seg = blockIdx.x;             // NBLK blocks
  unsigned n = blkCnt[seg]; if (n > LQ) n = LQ;
  const unsigned* segp = cand + (size_t)seg * LQ;
  for (unsigned i = gid; i < n; i += 16) doItem(segp[i]);

  unsigned ov = miscR[1]; if (ov > OVCAP) ov = OVCAP;
  const unsigned* ovp = cand + (size_t)NBLK * LQ;
  for (unsigned i = blockIdx.x * 16 + gid; i < ov; i += NBLK * 16) doItem(ovp[i]);
}

// ---------------------------------------------------------------------------
// finalize: gather codes + write index as float.
// ---------------------------------------------------------------------------
__global__ __launch_bounds__(256) void final_kernel(const float* __restrict__ embed,
                                                    const unsigned long long* __restrict__ pKey,
                                                    float* __restrict__ outQ,
                                                    float* __restrict__ indF) {
  int wid  = threadIdx.x >> 6;
  int lane = threadIdx.x & 63;
  int row  = blockIdx.x * 4 + wid;
  unsigned long long k = pKey[row];
  int idx = (int)(k & 8191ull);
  float4 v = *(const float4*)&embed[(size_t)idx * D + lane * 4];
  *(float4*)&outQ[(size_t)row * D + lane * 4] = v;
  if (lane == 0) indF[row] = (float)idx;
}

// ===========================================================================
// Fallback fp32 path (round-1, proven) — used if ws_size < WS_NEED3.
// ===========================================================================
#define BM_F 128
#define BN_F 128
#define BK_F 32
#define NSPLIT_F 4
#define SPLIT_CF (CODES / NSPLIT_F)

__global__ __launch_bounds__(256) void sq_kernel(const float* __restrict__ x,
                                                 const float* __restrict__ embed,
                                                 float* __restrict__ x2,
                                                 float* __restrict__ e2) {
  int wid  = threadIdx.x >> 6;
  int lane = threadIdx.x & 63;
  int rid  = blockIdx.x * 4 + wid;
  const float* base = (rid < NROWS) ? (x + (size_t)rid * D)
                                    : (embed + (size_t)(rid - NROWS) * D);
  float4 v = *(const float4*)(base + lane * 4);
  float p = v.x * v.x + v.y * v.y + v.z * v.z + v.w * v.w;
  #pragma unroll
  for (int off = 32; off > 0; off >>= 1) p += __shfl_down(p, off);
  if (lane == 0) {
    if (rid < NROWS) x2[rid] = p;
    else             e2[rid - NROWS] = p;
  }
}

__global__ __launch_bounds__(256) void argmin_f32_kernel(const float* __restrict__ x,
                                                         const float* __restrict__ embed,
                                                         const float* __restrict__ x2,
                                                         const float* __restrict__ e2,
                                                         float* __restrict__ pVal,
                                                         int* __restrict__ pIdx) {
  __shared__ float As[BK_F][BM_F];
  __shared__ float Bs[BK_F][BN_F];
  const int tid = threadIdx.x;
  const int ty = tid >> 4, tx = tid & 15;
  const int rowBase = blockIdx.x * BM_F;
  const int split = blockIdx.y;
  const int r0 = ty * 8, c0 = tx * 8;
  float bestV[8]; int bestI[8];
  #pragma unroll
  for (int i = 0; i < 8; i++) { bestV[i] = -INFINITY; bestI[i] = 0; }
  float x2r[8];
  #pragma unroll
  for (int i = 0; i < 8; i++) x2r[i] = x2[rowBase + r0 + i];
  for (int chunk = 0; chunk < SPLIT_CF / BN_F; ++chunk) {
    const int cBase = split * SPLIT_CF + chunk * BN_F;
    float acc[8][8];
    #pragma unroll
    for (int i = 0; i < 8; i++)
      #pragma unroll
      for (int j = 0; j < 8; j++) acc[i][j] = 0.0f;
    for (int kb = 0; kb < D / BK_F; ++kb) {
      #pragma unroll
      for (int i = 0; i < 4; i++) {
        int f4 = tid + i * 256;
        int rr = f4 >> 3, k4 = f4 & 7;
        float4 va = *(const float4*)&x[(size_t)(rowBase + rr) * D + kb * BK_F + k4 * 4];
        As[k4 * 4 + 0][rr] = va.x; As[k4 * 4 + 1][rr] = va.y;
        As[k4 * 4 + 2][rr] = va.z; As[k4 * 4 + 3][rr] = va.w;
        float4 vb = *(const float4*)&embed[(size_t)(cBase + rr) * D + kb * BK_F + k4 * 4];
        Bs[k4 * 4 + 0][rr] = vb.x; Bs[k4 * 4 + 1][rr] = vb.y;
        Bs[k4 * 4 + 2][rr] = vb.z; Bs[k4 * 4 + 3][rr] = vb.w;
      }
      __syncthreads();
      #pragma unroll 8
      for (int kk = 0; kk < BK_F; kk++) {
        float a[8], b[8];
        *(float4*)&a[0] = *(const float4*)&As[kk][r0];
        *(float4*)&a[4] = *(const float4*)&As[kk][r0 + 4];
        *(float4*)&b[0] = *(const float4*)&Bs[kk][c0];
        *(float4*)&b[4] = *(const float4*)&Bs[kk][c0 + 4];
        #pragma unroll
        for (int i = 0; i < 8; i++)
          #pragma unroll
          for (int j = 0; j < 8; j++)
            acc[i][j] = fmaf(a[i], b[j], acc[i][j]);
      }
      __syncthreads();
    }
    #pragma unroll
    for (int j = 0; j < 8; j++) {
      int c = cBase + c0 + j;
      float e2c = e2[c];
      #pragma unroll
      for (int i = 0; i < 8; i++) {
        float s  = __fadd_rn(x2r[i], e2c);
        float u  = __fmul_rn(2.0f, acc[i][j]);
        float d2 = fmaxf(__fsub_rn(s, u), 0.0f);
        float dist = -sqrtf(d2);
        if (dist > bestV[i]) { bestV[i] = dist; bestI[i] = c; }
      }
    }
  }
  __syncthreads();
  float* Vl = &As[0][0];
  int*   Il = (int*)&Bs[0][0];
  #pragma unroll
  for (int i = 0; i < 8; i++) {
    Vl[(ty * 16 + tx) * 8 + i] = bestV[i];
    Il[(ty * 16 + tx) * 8 + i] = bestI[i];
  }
  __syncthreads();
  if (tid < BM_F) {
    int rr = tid, tyr = rr >> 3, ii = rr & 7;
    float bv = -INFINITY; int bi = 0;
    #pragma unroll
    for (int t = 0; t < 16; t++) {
      float v = Vl[(tyr * 16 + t) * 8 + ii];
      int  iv = Il[(tyr * 16 + t) * 8 + ii];
      if (v > bv || (v == bv && iv < bi)) { bv = v; bi = iv; }
    }
    pVal[split * NROWS + rowBase + rr] = bv;
    pIdx[split * NROWS + rowBase + rr] = bi;
  }
}

__global__ __launch_bounds__(256) void merge_f32_kernel(const float* __restrict__ pVal,
                                                        const int* __restrict__ pIdx,
                                                        float* __restrict__ indF) {
  int row = blockIdx.x * 256 + threadIdx.x;
  if (row >= NROWS) return;
  float bv = -INFINITY; int bi = 0;
  #pragma unroll
  for (int s = 0; s < NSPLIT_F; s++) {
    float v = pVal[s * NROWS + row];
    int  iv = pIdx[s * NROWS + row];
    if (v > bv || (v == bv && iv < bi)) { bv = v; bi = iv; }
  }
  indF[row] = (float)bi;
}

__global__ __launch_bounds__(256) void gather_f32_kernel(const float* __restrict__ embed,
                                                         const float* __restrict__ indF,
                                                         float* __restrict__ outQ) {
  int wid = threadIdx.x >> 6, lane = threadIdx.x & 63;
  int row = blockIdx.x * 4 + wid;
  int idx = (int)indF[row];
  float4 v = *(const float4*)&embed[(size_t)idx * D + lane * 4];
  *(float4*)&outQ[(size_t)row * D + lane * 4] = v;
}

// ---------------------------------------------------------------------------
extern "C" void kernel_launch(void* const* d_in, const int* in_sizes, int n_in,
                              void* d_out, int out_size, void* d_ws, size_t ws_size,
                              hipStream_t stream) {
  const float* x     = (const float*)d_in[0];
  const float* embed = (const float*)d_in[1];
  float* o = (float*)d_out;

  if (ws_size >= WS_NEED3) {
    char* w = (char*)d_ws;
    unsigned short* A_h = (unsigned short*)(w + OFF_AH);
    float* x2 = (float*)(w + OFF_X2);
    float* nx = (float*)(w + OFF_NX);
    float* e2 = (float*)(w + OFF_E2);
    unsigned* rowMinU = (unsigned*)(w + OFF_RM);
    unsigned long long* pKey = (unsigned long long*)(w + OFF_PK);
    unsigned* misc = (unsigned*)(w + OFF_MISC);
    unsigned* blkCnt = (unsigned*)(w + OFF_BCNT);
    unsigned* cand = (unsigned*)(w + OFF_CAND);
    unsigned capN  = (unsigned)((ws_size - OFF_CAND) / 4ull);
    unsigned OVCAP = capN - (unsigned)(NBLK * LQ);

    unsigned short* E_h = (unsigned short*)o;      // 4MB scratch in quantize region
    float* indF = o + QOFF;

    init_kernel<<<128, 256, 0, stream>>>(misc, rowMinU, pKey);
    prep_kernel<<<(NROWS + CODES) / 4, 256, 0, stream>>>(x, embed, A_h, E_h, x2, nx, e2, misc);
    dim3 gridC(NROWS / BM, NSPL);
    gemm_pass<0><<<gridC, 256, 0, stream>>>(A_h, E_h, e2, nx, misc, rowMinU,
                                            cand, blkCnt, &misc[1], OVCAP);
    gemm_pass<1><<<gridC, 256, 0, stream>>>(A_h, E_h, e2, nx, misc, rowMinU,
                                            cand, blkCnt, &misc[1], OVCAP);
    refine_kernel<<<NBLK, 256, 0, stream>>>(x, embed, x2, e2, blkCnt, cand, misc,
                                            pKey, OVCAP);
    final_kernel<<<NROWS / 4, 256, 0, stream>>>(embed, pKey, o, indF);
  } else {
    // ---- fp32 fallback ----
    float* x2   = o;
    float* e2   = o + 32768;
    float* pVal = o + 65536;
    int*   pIdx = (int*)(o + 196608);
    float* indF = o + QOFF;
    sq_kernel<<<(NROWS + CODES) / 4, 256, 0, stream>>>(x, embed, x2, e2);
    dim3 gridB(NROWS / BM_F, NSPLIT_F);
    argmin_f32_kernel<<<gridB, 256, 0, stream>>>(x, embed, x2, e2, pVal, pIdx);
    merge_f32_kernel<<<NROWS / 256, 256, 0, stream>>>(pVal, pIdx, indF);
    gather_f32_kernel<<<NROWS / 4, 256, 0, stream>>>(embed, indF, o);
  }
}

// Round 9
// 444.417 us; speedup vs baseline: 1.8889x; 1.1214x over previous
//
#include <hip/hip_runtime.h>
#include <math.h>

#define D       256
#define NROWS   32768      // 8 * 4096
#define CODES   8192
#define QOFF    8388608    // index output offset (floats) in d_out

// ---------------- coarse GEMM config ----------------
#define BM      256
#define BN      256
#define NSPL    2
#define SPLC    (CODES / NSPL)    // 4096
#define NCHUNK  (SPLC / BN)       // 16
#define NSTEP   (NCHUNK * 4)      // 64 kb-steps (BK=64)
#define NBLK    256               // 128 rowTiles * NSPL
#define LQ      2048              // LDS candidate buffer entries (pass 2)

// rigorous collect margin (2M): 2*2*(2u+u^2)*||x||*||e||max, u=2^-9 (bf16 rn)
#define MARG_COEF 0.016f
#define MARG_ABS  0.10f

// ---------------- ws layout (bytes) ----------------
#define OFF_AH    0ull               // 32768*512 = 16777216
#define OFF_X2    16777216ull
#define OFF_NX    16908288ull
#define OFF_E2    17039360ull
#define OFF_RM    17072128ull        // 32768*4 (monotone-encoded float bits)
#define OFF_PK    17203200ull        // 32768*8
#define OFF_MISC  17465344ull        // [1]=ovCnt, [2]=neMaxBits
#define OFF_BCNT  17465600ull        // counts (<=1024 slots reserved)
#define OFF_CAND  17469696ull        // 4B entries: NBLK*LQ segmented + overflow
#define WS_NEED3  30052608ull        // proven available (rounds 5-8 ran MFMA path)

typedef __attribute__((ext_vector_type(8)))  short bf16x8;
typedef __attribute__((ext_vector_type(16))) float f32x16;

// Involutive swizzle for 128B LDS rows: bits 6:4 ^= row bits 2:0 (addr 9:7).
__device__ __forceinline__ int SWK(int b) { return b ^ (((b >> 7) & 7) << 4); }

__device__ __forceinline__ void gload16(const void* g, void* l) {
  __builtin_amdgcn_global_load_lds(
      (const __attribute__((address_space(1))) unsigned int*)g,
      (__attribute__((address_space(3))) unsigned int*)l, 16, 0, 0);
}

__device__ __forceinline__ unsigned short bf16rn(float x) {
  unsigned u = __float_as_uint(x);
  return (unsigned short)((u + 0x7fffu + ((u >> 16) & 1u)) >> 16);
}

// monotone float <-> uint (order-preserving incl. negatives)
__device__ __forceinline__ unsigned encf(float f) {
  unsigned b = __float_as_uint(f);
  return (b >> 31) ? ~b : (b | 0x80000000u);
}
__device__ __forceinline__ float decf(unsigned u) {
  return __uint_as_float((u >> 31) ? (u ^ 0x80000000u) : ~u);
}

// ---------------------------------------------------------------------------
__global__ __launch_bounds__(256) void init_kernel(unsigned* __restrict__ misc,
                                                   unsigned* __restrict__ rowMinU,
                                                   unsigned long long* __restrict__ pKey) {
  int i = blockIdx.x * 256 + threadIdx.x;   // 32768
  if (i < 16) misc[i] = 0u;
  rowMinU[i] = 0xFFFFFFFFu;
  pKey[i] = ~0ull;
}

// ---------------------------------------------------------------------------
// prep: bf16 h-planes + squared norms + neMax.
// ---------------------------------------------------------------------------
__global__ __launch_bounds__(256) void prep_kernel(const float* __restrict__ x,
                                                   const float* __restrict__ embed,
                                                   unsigned short* __restrict__ A_h,
                                                   unsigned short* __restrict__ E_h,
                                                   float* __restrict__ x2,
                                                   float* __restrict__ nx,
                                                   float* __restrict__ e2,
                                                   unsigned* __restrict__ misc) {
  int wid  = threadIdx.x >> 6;
  int lane = threadIdx.x & 63;
  int rid  = blockIdx.x * 4 + wid;   // 0..40959
  const float* src;
  unsigned short* dst;
  if (rid < NROWS) { src = x + (size_t)rid * D;               dst = A_h + (size_t)rid * D; }
  else             { src = embed + (size_t)(rid - NROWS) * D; dst = E_h + (size_t)(rid - NROWS) * D; }
  float4 v = *(const float4*)(src + lane * 4);
  ushort4 hv = make_ushort4(bf16rn(v.x), bf16rn(v.y), bf16rn(v.z), bf16rn(v.w));
  *(ushort4*)(dst + lane * 4) = hv;
  float p = v.x * v.x + v.y * v.y + v.z * v.z + v.w * v.w;
  #pragma unroll
  for (int off = 32; off > 0; off >>= 1) p += __shfl_down(p, off);
  if (lane == 0) {
    float n = sqrtf(p);
    if (rid < NROWS) { x2[rid] = p; nx[rid] = n; }
    else { e2[rid - NROWS] = p; atomicMax(&misc[2], __float_as_uint(n)); }
  }
}

// ---------------------------------------------------------------------------
// 256x256 double-buffered 2-phase GEMM, 8 waves (4 row-groups x 2 col-groups),
// wave tile 64x128 = 2x4 frags of mfma_f32_32x32x16_bf16 (6 ds_reads -> 8
// MFMAs per K16: ratio 1.33 vs 1.0 before).  Per kb-step: STAGE(next) ->
// compute(cur) -> [chunk-end epilogue] -> one __syncthreads.
// MODE0: per-row min of q = e2 - 2*xe.  MODE1: collect q <= rowMin + margin.
// Identical engine => bit-identical q between passes.
// ---------------------------------------------------------------------------
template<int MODE>
__global__ __launch_bounds__(512, 2) void gemm_pass(
    const unsigned short* __restrict__ A_h,
    const unsigned short* __restrict__ E_h,
    const float* __restrict__ e2g,
    const float* __restrict__ nxg,
    const unsigned* __restrict__ miscR,
    unsigned* __restrict__ rowMinU,
    unsigned* __restrict__ cand,        // NBLK*LQ segmented + overflow tail
    unsigned* __restrict__ blkCnt,
    unsigned* __restrict__ ovCnt,       // &misc[1]
    unsigned OVCAP) {
  __shared__ __align__(16) char As0[32768];   // 256 rows x 128B (BK=64)
  __shared__ __align__(16) char As1[32768];
  __shared__ __align__(16) char Bs0[32768];
  __shared__ __align__(16) char Bs1[32768];
  __shared__ unsigned lbuf[MODE ? LQ : 1];
  __shared__ unsigned lcnt;

  const int tid  = threadIdx.x;
  const int lane = tid & 63;
  const int wave = tid >> 6;            // 0..7
  const int wm = wave >> 1;             // 0..3  row group (64 rows)
  const int wn = wave & 1;              // 0..1  col group (128 cols)
  const int l31 = lane & 31;
  const int hi16 = (lane >> 5) << 4;
  const int lh4  = (lane >> 5) << 2;
  const int rowBase = blockIdx.x * BM;
  const int split   = blockIdx.y;
  const int seg     = blockIdx.y * 128 + blockIdx.x;

  // per-lane read geometry: row&7 == l31&7 for both A and B fragment rows,
  // so one XOR key serves all frags; f/g offsets are compile-time immediates.
  const int Ccom = hi16 ^ ((l31 & 7) << 4);
  const int Aoff = (wm * 64 + l31) << 7;    // + f*4096 + (Ccom^ks*32)
  const int Boff = (wn * 128 + l31) << 7;   // + g*4096 + (Ccom^ks*32)

  // staging slots: 4 gload16 each for A and B per kb step (32KB tiles)
  int stRow[4], stCo[4], stDst[4];
  #pragma unroll
  for (int i = 0; i < 4; i++) {
    int q = i * 512 + tid;          // 0..2047 16B-slot
    int u = SWK(q << 4);            // logical byte (involution)
    stRow[i] = u >> 7;
    stCo[i]  = u & 127;
    stDst[i] = (q & ~63) << 4;      // wave-uniform base
  }

  auto STAGE = [&](char* Ad, char* Bd, int s) {
    int cc = s >> 2, kb = s & 3;
    const int cBase = split * SPLC + cc * BN;
    #pragma unroll
    for (int i = 0; i < 4; i++) {
      gload16((const char*)A_h + (((size_t)(rowBase + stRow[i])) << 9) + (kb << 7) + stCo[i],
              Ad + stDst[i]);
      gload16((const char*)E_h + (((size_t)(cBase + stRow[i])) << 9) + (kb << 7) + stCo[i],
              Bd + stDst[i]);
    }
  };

  // ---- prologue: stage step 0; state init overlaps the loads ----
  STAGE(As0, Bs0, 0);
  if (MODE == 1 && tid == 0) lcnt = 0;

  float state[2][16];   // MODE0: running min q; MODE1: thresholds
  if (MODE == 0) {
    #pragma unroll
    for (int fm = 0; fm < 2; fm++)
      #pragma unroll
      for (int rg = 0; rg < 16; rg++) state[fm][rg] = INFINITY;
  } else {
    float neMaxF = __uint_as_float(miscR[2]);
    #pragma unroll
    for (int fm = 0; fm < 2; fm++)
      #pragma unroll
      for (int rg = 0; rg < 16; rg++) {
        int row = rowBase + wm * 64 + fm * 32 + ((rg & 3) + 8 * (rg >> 2)) + lh4;
        state[fm][rg] = decf(rowMinU[row]) + fmaf(MARG_COEF * nxg[row], neMaxF, MARG_ABS);
      }
  }

  f32x16 acc[2][4];
  #pragma unroll
  for (int i = 0; i < 2; i++)
    #pragma unroll
    for (int j = 0; j < 4; j++) acc[i][j] = (f32x16)(0.0f);

  __syncthreads();   // step-0 stage landed

  for (int s = 0; s < NSTEP; ++s) {
    char* Ac = (s & 1) ? As1 : As0;
    char* Bc = (s & 1) ? Bs1 : Bs0;
    if (s + 1 < NSTEP) STAGE((s & 1) ? As0 : As1, (s & 1) ? Bs0 : Bs1, s + 1);

    #pragma unroll
    for (int ks = 0; ks < 4; ++ks) {
      const int off = Ccom ^ (ks << 5);
      bf16x8 a0 = *(const bf16x8*)(Ac + Aoff + off);
      bf16x8 a1 = *(const bf16x8*)(Ac + Aoff + 4096 + off);
      bf16x8 b0 = *(const bf16x8*)(Bc + Boff + off);
      bf16x8 b1 = *(const bf16x8*)(Bc + Boff + 4096 + off);
      bf16x8 b2 = *(const bf16x8*)(Bc + Boff + 8192 + off);
      bf16x8 b3 = *(const bf16x8*)(Bc + Boff + 12288 + off);
      acc[0][0] = __builtin_amdgcn_mfma_f32_32x32x16_bf16(a0, b0, acc[0][0], 0, 0, 0);
      acc[1][0] = __builtin_amdgcn_mfma_f32_32x32x16_bf16(a1, b0, acc[1][0], 0, 0, 0);
      acc[0][1] = __builtin_amdgcn_mfma_f32_32x32x16_bf16(a0, b1, acc[0][1], 0, 0, 0);
      acc[1][1] = __builtin_amdgcn_mfma_f32_32x32x16_bf16(a1, b1, acc[1][1], 0, 0, 0);
      acc[0][2] = __builtin_amdgcn_mfma_f32_32x32x16_bf16(a0, b2, acc[0][2], 0, 0, 0);
      acc[1][2] = __builtin_amdgcn_mfma_f32_32x32x16_bf16(a1, b2, acc[1][2], 0, 0, 0);
      acc[0][3] = __builtin_amdgcn_mfma_f32_32x32x16_bf16(a0, b3, acc[0][3], 0, 0, 0);
      acc[1][3] = __builtin_amdgcn_mfma_f32_32x32x16_bf16(a1, b3, acc[1][3], 0, 0, 0);
    }

    if ((s & 3) == 3) {
      // chunk epilogue: q = e2 - 2*xe (C/D map: row=(rg&3)+8*(rg>>2)+lh4, col=l31)
      const int cc = s >> 2;
      const int cBase = split * SPLC + cc * BN;
      if (MODE == 0) {
        #pragma unroll
        for (int g = 0; g < 4; g++) {
          float e2c = e2g[cBase + wn * 128 + g * 32 + l31];
          #pragma unroll
          for (int fm = 0; fm < 2; fm++)
            #pragma unroll
            for (int rg = 0; rg < 16; rg++)
              state[fm][rg] = fminf(state[fm][rg], fmaf(acc[fm][g][rg], -2.0f, e2c));
        }
      } else {
        #pragma unroll
        for (int g = 0; g < 4; g++) {
          int col = cBase + wn * 128 + g * 32 + l31;
          float e2c = e2g[col];
          #pragma unroll
          for (int fm = 0; fm < 2; fm++)
            #pragma unroll
            for (int rg = 0; rg < 16; rg++) {
              float q = fmaf(acc[fm][g][rg], -2.0f, e2c);
              if (q <= state[fm][rg]) {
                int row = rowBase + wm * 64 + fm * 32 + ((rg & 3) + 8 * (rg >> 2)) + lh4;
                unsigned en = (unsigned)((row << 13) | col);
                unsigned p = atomicAdd(&lcnt, 1u);
                if (p < LQ) lbuf[p] = en;
                else { unsigned gp = atomicAdd(ovCnt, 1u);
                       if (gp < OVCAP) cand[(size_t)NBLK * LQ + gp] = en; }
              }
            }
        }
      }
      #pragma unroll
      for (int i = 0; i < 2; i++)
        #pragma unroll
        for (int j = 0; j < 4; j++) acc[i][j] = (f32x16)(0.0f);
    }

    __syncthreads();   // drains next-step stage; guards buffer swap
  }

  if (MODE == 0) {
    #pragma unroll
    for (int fm = 0; fm < 2; fm++)
      #pragma unroll
      for (int rg = 0; rg < 16; rg++) {
        float v = state[fm][rg];
        #pragma unroll
        for (int off = 1; off < 32; off <<= 1) v = fminf(v, __shfl_xor(v, off));
        if (l31 == 0) {
          int row = rowBase + wm * 64 + fm * 32 + ((rg & 3) + 8 * (rg >> 2)) + lh4;
          atomicMin(&rowMinU[row], encf(v));
        }
      }
  } else {
    unsigned n = lcnt; if (n > LQ) n = LQ;
    for (unsigned i = tid; i < n; i += 512) cand[(size_t)seg * LQ + i] = lbuf[i];
    if (tid == 0) blkCnt[seg] = n;
  }
}

// ---------------------------------------------------------------------------
// refine: 16-lane groups, fp64 dot, exact ref combine, u64 atomicMin key.
// ---------------------------------------------------------------------------
__global__ __launch_bounds__(256) void refine_kernel(const float* __restrict__ x,
                                                     const float* __restrict__ embed,
                                                     const float* __restrict__ x2g,
                                                     const float* __restrict__ e2g,
                                                     const unsigned* __restrict__ blkCnt,
                                                     const unsigned* __restrict__ cand,
                                                     const unsigned* __restrict__ miscR,
                                                     unsigned long long* __restrict__ pKey,
                                                     unsigned OVCAP) {
  const int tid = threadIdx.x;
  const int l16 = tid & 15;
  const int gid = tid >> 4;

  auto doItem = [&](unsigned pk) {
    int row = (int)(pk >> 13), col = (int)(pk & 8191u);
    double s = 0.0;
    #pragma unroll
    for (int p = 0; p < 4; p++) {
      float4 xv = *(const float4*)&x[(size_t)row * D + p * 64 + l16 * 4];
      float4 ev = *(const float4*)&embed[(size_t)col * D + p * 64 + l16 * 4];
      s = fma((double)xv.x, (double)ev.x, s);
      s = fma((double)xv.y, (double)ev.y, s);
      s = fma((double)xv.z, (double)ev.z, s);
      s = fma((double)xv.w, (double)ev.w, s);
    }
    #pragma unroll
    for (int off = 1; off < 16; off <<= 1) s += __shfl_xor(s, off);
    if (l16 == 0) {
      float xef = (float)s;
      float ss  = __fadd_rn(x2g[row], e2g[col]);
      float d2  = __fsub_rn(ss, __fmul_rn(2.0f, xef));
      d2 = fmaxf(d2, 0.0f);
      float sq = sqrtf(d2);
      unsigned long long key =
          ((unsigned long long)__float_as_uint(sq) << 32) | (unsigned)col;
      atomicMin(pKey + row, key);
    }
  };

  unsigned seg = blockIdx.x;             // NBLK blocks
  unsigned n = blkCnt[seg]; if (n > LQ) n = LQ;
  const unsigned* segp = cand + (size_t)seg * LQ;
  for (unsigned i = gid; i < n; i += 16) doItem(segp[i]);

  unsigned ov = miscR[1]; if (ov > OVCAP) ov = OVCAP;
  const unsigned* ovp = cand + (size_t)NBLK * LQ;
  for (unsigned i = blockIdx.x * 16 + gid; i < ov; i += NBLK * 16) doItem(ovp[i]);
}

// ---------------------------------------------------------------------------
// finalize: gather codes + write index as float.
// ---------------------------------------------------------------------------
__global__ __launch_bounds__(256) void final_kernel(const float* __restrict__ embed,
                                                    const unsigned long long* __restrict__ pKey,
                                                    float* __restrict__ outQ,
                                                    float* __restrict__ indF) {
  int wid  = threadIdx.x >> 6;
  int lane = threadIdx.x & 63;
  int row  = blockIdx.x * 4 + wid;
  unsigned long long k = pKey[row];
  int idx = (int)(k & 8191ull);
  float4 v = *(const float4*)&embed[(size_t)idx * D + lane * 4];
  *(float4*)&outQ[(size_t)row * D + lane * 4] = v;
  if (lane == 0) indF[row] = (float)idx;
}

// ===========================================================================
// Fallback fp32 path (round-1, proven) — used if ws_size < WS_NEED3.
// ===========================================================================
#define BM_F 128
#define BN_F 128
#define BK_F 32
#define NSPLIT_F 4
#define SPLIT_CF (CODES / NSPLIT_F)

__global__ __launch_bounds__(256) void sq_kernel(const float* __restrict__ x,
                                                 const float* __restrict__ embed,
                                                 float* __restrict__ x2,
                                                 float* __restrict__ e2) {
  int wid  = threadIdx.x >> 6;
  int lane = threadIdx.x & 63;
  int rid  = blockIdx.x * 4 + wid;
  const float* base = (rid < NROWS) ? (x + (size_t)rid * D)
                                    : (embed + (size_t)(rid - NROWS) * D);
  float4 v = *(const float4*)(base + lane * 4);
  float p = v.x * v.x + v.y * v.y + v.z * v.z + v.w * v.w;
  #pragma unroll
  for (int off = 32; off > 0; off >>= 1) p += __shfl_down(p, off);
  if (lane == 0) {
    if (rid < NROWS) x2[rid] = p;
    else             e2[rid - NROWS] = p;
  }
}

__global__ __launch_bounds__(256) void argmin_f32_kernel(const float* __restrict__ x,
                                                         const float* __restrict__ embed,
                                                         const float* __restrict__ x2,
                                                         const float* __restrict__ e2,
                                                         float* __restrict__ pVal,
                                                         int* __restrict__ pIdx) {
  __shared__ float As[BK_F][BM_F];
  __shared__ float Bs[BK_F][BN_F];
  const int tid = threadIdx.x;
  const int ty = tid >> 4, tx = tid & 15;
  const int rowBase = blockIdx.x * BM_F;
  const int split = blockIdx.y;
  const int r0 = ty * 8, c0 = tx * 8;
  float bestV[8]; int bestI[8];
  #pragma unroll
  for (int i = 0; i < 8; i++) { bestV[i] = -INFINITY; bestI[i] = 0; }
  float x2r[8];
  #pragma unroll
  for (int i = 0; i < 8; i++) x2r[i] = x2[rowBase + r0 + i];
  for (int chunk = 0; chunk < SPLIT_CF / BN_F; ++chunk) {
    const int cBase = split * SPLIT_CF + chunk * BN_F;
    float acc[8][8];
    #pragma unroll
    for (int i = 0; i < 8; i++)
      #pragma unroll
      for (int j = 0; j < 8; j++) acc[i][j] = 0.0f;
    for (int kb = 0; kb < D / BK_F; ++kb) {
      #pragma unroll
      for (int i = 0; i < 4; i++) {
        int f4 = tid + i * 256;
        int rr = f4 >> 3, k4 = f4 & 7;
        float4 va = *(const float4*)&x[(size_t)(rowBase + rr) * D + kb * BK_F + k4 * 4];
        As[k4 * 4 + 0][rr] = va.x; As[k4 * 4 + 1][rr] = va.y;
        As[k4 * 4 + 2][rr] = va.z; As[k4 * 4 + 3][rr] = va.w;
        float4 vb = *(const float4*)&embed[(size_t)(cBase + rr) * D + kb * BK_F + k4 * 4];
        Bs[k4 * 4 + 0][rr] = vb.x; Bs[k4 * 4 + 1][rr] = vb.y;
        Bs[k4 * 4 + 2][rr] = vb.z; Bs[k4 * 4 + 3][rr] = vb.w;
      }
      __syncthreads();
      #pragma unroll 8
      for (int kk = 0; kk < BK_F; kk++) {
        float a[8], b[8];
        *(float4*)&a[0] = *(const float4*)&As[kk][r0];
        *(float4*)&a[4] = *(const float4*)&As[kk][r0 + 4];
        *(float4*)&b[0] = *(const float4*)&Bs[kk][c0];
        *(float4*)&b[4] = *(const float4*)&Bs[kk][c0 + 4];
        #pragma unroll
        for (int i = 0; i < 8; i++)
          #pragma unroll
          for (int j = 0; j < 8; j++)
            acc[i][j] = fmaf(a[i], b[j], acc[i][j]);
      }
      __syncthreads();
    }
    #pragma unroll
    for (int j = 0; j < 8; j++) {
      int c = cBase + c0 + j;
      float e2c = e2[c];
      #pragma unroll
      for (int i = 0; i < 8; i++) {
        float s  = __fadd_rn(x2r[i], e2c);
        float u  = __fmul_rn(2.0f, acc[i][j]);
        float d2 = fmaxf(__fsub_rn(s, u), 0.0f);
        float dist = -sqrtf(d2);
        if (dist > bestV[i]) { bestV[i] = dist; bestI[i] = c; }
      }
    }
  }
  __syncthreads();
  float* Vl = &As[0][0];
  int*   Il = (int*)&Bs[0][0];
  #pragma unroll
  for (int i = 0; i < 8; i++) {
    Vl[(ty * 16 + tx) * 8 + i] = bestV[i];
    Il[(ty * 16 + tx) * 8 + i] = bestI[i];
  }
  __syncthreads();
  if (tid < BM_F) {
    int rr = tid, tyr = rr >> 3, ii = rr & 7;
    float bv = -INFINITY; int bi = 0;
    #pragma unroll
    for (int t = 0; t < 16; t++) {
      float v = Vl[(tyr * 16 + t) * 8 + ii];
      int  iv = Il[(tyr * 16 + t) * 8 + ii];
      if (v > bv || (v == bv && iv < bi)) { bv = v; bi = iv; }
    }
    pVal[split * NROWS + rowBase + rr] = bv;
    pIdx[split * NROWS + rowBase + rr] = bi;
  }
}

__global__ __launch_bounds__(256) void merge_f32_kernel(const float* __restrict__ pVal,
                                                        const int* __restrict__ pIdx,
                                                        float* __restrict__ indF) {
  int row = blockIdx.x * 256 + threadIdx.x;
  if (row >= NROWS) return;
  float bv = -INFINITY; int bi = 0;
  #pragma unroll
  for (int s = 0; s < NSPLIT_F; s++) {
    float v = pVal[s * NROWS + row];
    int  iv = pIdx[s * NROWS + row];
    if (v > bv || (v == bv && iv < bi)) { bv = v; bi = iv; }
  }
  indF[row] = (float)bi;
}

__global__ __launch_bounds__(256) void gather_f32_kernel(const float* __restrict__ embed,
                                                         const float* __restrict__ indF,
                                                         float* __restrict__ outQ) {
  int wid = threadIdx.x >> 6, lane = threadIdx.x & 63;
  int row = blockIdx.x * 4 + wid;
  int idx = (int)indF[row];
  float4 v = *(const float4*)&embed[(size_t)idx * D + lane * 4];
  *(float4*)&outQ[(size_t)row * D + lane * 4] = v;
}

// ---------------------------------------------------------------------------
extern "C" void kernel_launch(void* const* d_in, const int* in_sizes, int n_in,
                              void* d_out, int out_size, void* d_ws, size_t ws_size,
                              hipStream_t stream) {
  const float* x     = (const float*)d_in[0];
  const float* embed = (const float*)d_in[1];
  float* o = (float*)d_out;

  if (ws_size >= WS_NEED3) {
    char* w = (char*)d_ws;
    unsigned short* A_h = (unsigned short*)(w + OFF_AH);
    float* x2 = (float*)(w + OFF_X2);
    float* nx = (float*)(w + OFF_NX);
    float* e2 = (float*)(w + OFF_E2);
    unsigned* rowMinU = (unsigned*)(w + OFF_RM);
    unsigned long long* pKey = (unsigned long long*)(w + OFF_PK);
    unsigned* misc = (unsigned*)(w + OFF_MISC);
    unsigned* blkCnt = (unsigned*)(w + OFF_BCNT);
    unsigned* cand = (unsigned*)(w + OFF_CAND);
    unsigned capN  = (unsigned)((ws_size - OFF_CAND) / 4ull);
    unsigned OVCAP = capN - (unsigned)(NBLK * LQ);

    unsigned short* E_h = (unsigned short*)o;      // 4MB scratch in quantize region
    float* indF = o + QOFF;

    init_kernel<<<128, 256, 0, stream>>>(misc, rowMinU, pKey);
    prep_kernel<<<(NROWS + CODES) / 4, 256, 0, stream>>>(x, embed, A_h, E_h, x2, nx, e2, misc);
    dim3 gridC(NROWS / BM, NSPL);
    gemm_pass<0><<<gridC, 512, 0, stream>>>(A_h, E_h, e2, nx, misc, rowMinU,
                                            cand, blkCnt, &misc[1], OVCAP);
    gemm_pass<1><<<gridC, 512, 0, stream>>>(A_h, E_h, e2, nx, misc, rowMinU,
                                            cand, blkCnt, &misc[1], OVCAP);
    refine_kernel<<<NBLK, 256, 0, stream>>>(x, embed, x2, e2, blkCnt, cand, misc,
                                            pKey, OVCAP);
    final_kernel<<<NROWS / 4, 256, 0, stream>>>(embed, pKey, o, indF);
  } else {
    // ---- fp32 fallback ----
    float* x2   = o;
    float* e2   = o + 32768;
    float* pVal = o + 65536;
    int*   pIdx = (int*)(o + 196608);
    float* indF = o + QOFF;
    sq_kernel<<<(NROWS + CODES) / 4, 256, 0, stream>>>(x, embed, x2, e2);
    dim3 gridB(NROWS / BM_F, NSPLIT_F);
    argmin_f32_kernel<<<gridB, 256, 0, stream>>>(x, embed, x2, e2, pVal, pIdx);
    merge_f32_kernel<<<NROWS / 256, 256, 0, stream>>>(pVal, pIdx, indF);
    gather_f32_kernel<<<NROWS / 4, 256, 0, stream>>>(embed, indF, o);
  }
}